// Round 3
// baseline (175.382 us; speedup 1.0000x reference)
//
#include <hip/hip_runtime.h>

// ShiftLayer: out[b,t,c] = in[b, t+off[c], c], off per c%3 = {0: identity, 1: t-1, 2: t+1},
// zero padding at t boundaries. B=8, L=8192, C=384 (divisible by 3), fp32 in/out.
//
// v4: v3 + forced load batching. v3's rocprof showed VGPR_Count=32 -> the compiler
// re-serialized the "batched" 10-row load into low-pressure load/consume chunks,
// leaving ~3 loads in flight (latency-bound, 2.6 TB/s). Here an empty asm with
// "+v" constraints on all 10 row registers forces them simultaneously live after
// the load block, so all 10 global_load_dwordx4 issue back-to-back per wave
// before the single s_waitcnt drain. Only this changed vs v3 (clean A/B).

constexpr int kB = 8;
constexpr int kL = 8192;
constexpr int kC = 384;
constexpr int kV = 4;                    // fp32 elements per 16B vector
constexpr int kCV = kC / kV;             // 96 vectors per (b,t) row
constexpr int kT = 8;                    // timesteps per thread
constexpr int kTB = kL / kT;             // 1024 t-blocks
constexpr int kThreads = 256;
constexpr int kTotalThreads = kB * kTB * kCV;        // 786,432
constexpr int kBlocks = kTotalThreads / kThreads;    // 3072 (exact)

typedef __attribute__((ext_vector_type(4))) float f32x4;

__global__ __launch_bounds__(256) void ShiftLayer_66932770341347_kernel(
    const f32x4* __restrict__ in, f32x4* __restrict__ out) {
  int idx = blockIdx.x * kThreads + threadIdx.x;  // grid is exact, no tail check

  int v = idx % kCV;                 // vector column within the channel row
  int rest = idx / kCV;
  int tb = rest % kTB;               // t-block index
  int b = rest / kTB;                // batch
  int t0 = tb * kT;

  const f32x4* __restrict__ base = in + (long)b * (kL * kCV) + v;
  f32x4* __restrict__ obase = out + (long)b * (kL * kCV) + v;

  const f32x4 zero = {0.f, 0.f, 0.f, 0.f};

  // Batched loads: rows t0-1 .. t0+kT, clamped at the edges (legal address;
  // value overwritten below).
  f32x4 r[kT + 2];
#pragma unroll
  for (int i = 0; i < kT + 2; ++i) {
    int t = t0 - 1 + i;
    int tc = t < 0 ? 0 : (t >= kL ? kL - 1 : t);
    r[i] = base[(long)tc * kCV];
  }

  // Force all 10 row values simultaneously live here -> compiler must issue all
  // 10 loads before this point (no load/consume re-serialization). Rule-17
  // liveness barrier; costs 0 instructions.
  asm volatile(""
               : "+v"(r[0]), "+v"(r[1]), "+v"(r[2]), "+v"(r[3]), "+v"(r[4]),
                 "+v"(r[5]), "+v"(r[6]), "+v"(r[7]), "+v"(r[8]), "+v"(r[9]));

  if (t0 == 0) r[0] = zero;              // prev of t=0 is the zero pad
  if (t0 + kT == kL) r[kT + 1] = zero;   // next of t=L-1 is the zero pad

  // Base channel of this vector: c0 = 4v; c0 % 3 == v % 3 (4 ≡ 1 mod 3).
  int m0 = v % 3;

#pragma unroll
  for (int i = 0; i < kT; ++i) {
    f32x4 prev = r[i];
    f32x4 cur = r[i + 1];
    f32x4 next = r[i + 2];

    f32x4 o;
#pragma unroll
    for (int j = 0; j < kV; ++j) {
      int m = m0 + j;                // (v + j) % 3; m0 <= 2, j <= 3 -> m <= 5
      m = (m >= 3) ? m - 3 : m;
      // m==0 -> identity (cur), m==1 -> read t-1 (prev), m==2 -> read t+1 (next)
      o[j] = (m == 0) ? cur[j] : ((m == 1) ? prev[j] : next[j]);
    }
    obase[(long)(t0 + i) * kCV] = o;
  }
}

extern "C" void kernel_launch(void* const* d_in, const int* in_sizes, int n_in,
                              void* d_out, int out_size, void* d_ws, size_t ws_size,
                              hipStream_t stream) {
  const f32x4* in = reinterpret_cast<const f32x4*>(d_in[0]);
  f32x4* out = reinterpret_cast<f32x4*>(d_out);
  ShiftLayer_66932770341347_kernel<<<kBlocks, kThreads, 0, stream>>>(in, out);
}

// Round 4
// 171.082 us; speedup vs baseline: 1.0251x; 1.0251x over previous
//
#include <hip/hip_runtime.h>

// ShiftLayer: out[b,t,c] = in[b, t+off[c], c], off per c%3 = {0: identity, 1: t-1, 2: t+1},
// zero padding at t boundaries. B=8, L=8192, C=384 (divisible by 3), fp32 in/out.
//
// v5: v1 structure (the empirical best, ~54us kernel) with kT=2. Findings so far:
// deep t-coarsening (kT=8) LOST to v1 despite 3x fewer read requests -> the
// kernel is TLP/latency-bound, not request-bound. v5 keeps v1's 32-waves/CU
// residency (12288 blocks) and its trivially-batchable independent-load pattern
// (4 loads, low register pressure, all before any store so in-order vmcnt never
// waits on store completion), while halving read amplification (3.0x -> 2.0x)
// and cutting vmem instructions per output vector from 4 to 3.

constexpr int kB = 8;
constexpr int kL = 8192;
constexpr int kC = 384;
constexpr int kV = 4;                     // fp32 elements per 16B vector
constexpr int kCV = kC / kV;              // 96 vectors per (b,t) row
constexpr int kT = 2;                     // timesteps per thread
constexpr int kPairs = kL / kT;           // 4096 row-pairs
constexpr int kThreads = 256;
constexpr int kTotalThreads = kB * kPairs * kCV;     // 3,145,728
constexpr int kBlocks = kTotalThreads / kThreads;    // 12288 (exact)

typedef __attribute__((ext_vector_type(4))) float f32x4;

__global__ __launch_bounds__(256) void ShiftLayer_66932770341347_kernel(
    const f32x4* __restrict__ in, f32x4* __restrict__ out) {
  int idx = blockIdx.x * kThreads + threadIdx.x;  // grid exact, no tail check

  int v = idx % kCV;                  // vector column within the channel row
  int rest = idx / kCV;
  int tp = rest % kPairs;             // row-pair index
  int b = rest / kPairs;              // batch
  int t0 = tp * 2;                    // first of the two rows this thread owns

  const f32x4* __restrict__ base = in + (long)b * (kL * kCV) + v;
  f32x4* __restrict__ obase = out + (long)b * (kL * kCV) + v;

  const f32x4 zero = {0.f, 0.f, 0.f, 0.f};

  // Rows t0-1 .. t0+2, edges clamped to a legal address (value fixed below).
  int tm = (t0 == 0) ? 0 : t0 - 1;
  int tn = (t0 + 2 < kL) ? t0 + 2 : kL - 1;

  // 4 independent loads, all issued before any store.
  f32x4 r0 = base[(long)tm * kCV];
  f32x4 r1 = base[(long)t0 * kCV];
  f32x4 r2 = base[(long)(t0 + 1) * kCV];
  f32x4 r3 = base[(long)tn * kCV];

  // Keep all 4 rows live here so the loads issue back-to-back (16 regs: cheap).
  asm volatile("" : "+v"(r0), "+v"(r1), "+v"(r2), "+v"(r3));

  if (t0 == 0) r0 = zero;             // prev of t=0 is the zero pad
  if (t0 + 2 == kL) r3 = zero;        // next of t=L-1 is the zero pad

  // Base channel of this vector: c0 = 4v; c0 % 3 == v % 3 (4 ≡ 1 mod 3).
  int m0 = v % 3;

  f32x4 o0, o1;
#pragma unroll
  for (int j = 0; j < kV; ++j) {
    int m = m0 + j;                   // (v + j) % 3; m0 <= 2, j <= 3 -> m <= 5
    m = (m >= 3) ? m - 3 : m;
    // m==0 -> identity, m==1 -> read t-1, m==2 -> read t+1
    o0[j] = (m == 0) ? r1[j] : ((m == 1) ? r0[j] : r2[j]);  // row t0
    o1[j] = (m == 0) ? r2[j] : ((m == 1) ? r1[j] : r3[j]);  // row t0+1
  }

  obase[(long)t0 * kCV] = o0;
  obase[(long)(t0 + 1) * kCV] = o1;
}

extern "C" void kernel_launch(void* const* d_in, const int* in_sizes, int n_in,
                              void* d_out, int out_size, void* d_ws, size_t ws_size,
                              hipStream_t stream) {
  const f32x4* in = reinterpret_cast<const f32x4*>(d_in[0]);
  f32x4* out = reinterpret_cast<f32x4*>(d_out);
  ShiftLayer_66932770341347_kernel<<<kBlocks, kThreads, 0, stream>>>(in, out);
}